// Round 3
// baseline (317.939 us; speedup 1.0000x reference)
//
#include <hip/hip_runtime.h>

// Perceive3D: x (B=4, C=16, D=64, H=64, W=64) fp32, edge-padded 3^3 stencil,
// 4 separable kernels (identity, sobel-W, sobel-H, sobel-D), out (B,4,C,D,H,W).
//
// R3b (third submit; rounds 1-2 died in broker infra before any kernel
// verdict): separable d-marching. Per (bc, h, w-quad) thread, march d in
// chunks of DCHUNK with a 3-plane register ring of h-reduced partials:
//   u = S_w*x, v = D_w*x              (per row: 1 dwordx4 load + 2 shuffles)
//   A = S_h*u, Bv = S_h*v, Cc = D_h*u (per plane: 3 rows)
//   sx = S_d*Bv/16, sy = S_d*Cc/16, sz = D_d*A/16, center = raw row.
// Per output plane position: 3 loads (was 9 in R2), 6 shuffles (was 18),
// ~2.5x less VALU. Plane d+2 rows prefetched one iteration ahead. Stores:
// 4 wave-contiguous 1 KB nontemporal dwordx4 streams (unchanged from R2).
// Memory floor: 64 MB in + 268 MB out => ~55 us at 6.3 TB/s.

#define B_ 4
#define C_ 16
#define D_ 64
#define H_ 64
#define W_ 64
#define DCHUNK 8

typedef float float4v __attribute__((ext_vector_type(4)));

__device__ __forceinline__ void row_uv(float4v q, int quad, float4v& u, float4v& v)
{
    // +-1 shifted vectors via cross-lane; quad 0/15 edge-clamp.
    float left  = __shfl_up(q.w, 1);
    float right = __shfl_down(q.x, 1);
    if (quad == 0)  left  = q.x;    // w=-1 -> clamp to w=0
    if (quad == 15) right = q.w;    // w=64 -> clamp to w=63
    float4v am = { left, q.x, q.y, q.z };   // x[w-1]
    float4v ap = { q.y, q.z, q.w, right };  // x[w+1]
    u = am + 2.0f * q + ap;                 // smooth along W
    v = ap - am;                            // diff along W
}

__device__ __forceinline__ void make_plane(float4v qm, float4v qc, float4v qp,
                                           int quad,
                                           float4v& A, float4v& Bv, float4v& Cc)
{
    float4v um, vm, uc, vc, up, vp;
    row_uv(qm, quad, um, vm);
    row_uv(qc, quad, uc, vc);
    row_uv(qp, quad, up, vp);
    A  = um + 2.0f * uc + up;   // S_h * u
    Bv = vm + 2.0f * vc + vp;   // S_h * v
    Cc = up - um;               // D_h * u
}

__global__ __launch_bounds__(256) void perceive3d_kernel(
    const float* __restrict__ x, float* __restrict__ out)
{
    const int lane = threadIdx.x;          // 0..63
    const int quad = lane & 15;            // w = 4*quad
    const int hsub = lane >> 4;            // 0..3
    const int h    = blockIdx.x * 16 + threadIdx.y * 4 + hsub;
    const int d0   = blockIdx.y * DCHUNK;
    const int bc   = blockIdx.z;           // b*C + c
    const int b    = bc >> 4;
    const int c    = bc & 15;

    const float* xb = x + (size_t)bc * (D_ * H_ * W_) + 4 * quad;

    const int hm = (h == 0) ? 0 : h - 1;
    const int hp = (h == H_ - 1) ? H_ - 1 : h + 1;
    const int rm = hm * W_;
    const int rc = h  * W_;
    const int rp = hp * W_;

    // ring: slot0 = plane d-1, slot1 = plane d; m* = rows of plane d+1 in flight
    float4v A0, Bv0, Cc0, A1, Bv1, Cc1, q1;
    float4v m0, m1, m2;

    {
        const float* p0 = xb + ((d0 == 0) ? 0 : d0 - 1) * (H_ * W_);
        float4v a  = *(const float4v*)(p0 + rm);
        float4v bq = *(const float4v*)(p0 + rc);
        float4v cq = *(const float4v*)(p0 + rp);
        make_plane(a, bq, cq, quad, A0, Bv0, Cc0);

        const float* p1 = xb + d0 * (H_ * W_);
        a  = *(const float4v*)(p1 + rm);
        bq = *(const float4v*)(p1 + rc);
        cq = *(const float4v*)(p1 + rp);
        make_plane(a, bq, cq, quad, A1, Bv1, Cc1);
        q1 = bq;                                   // raw center row at d0

        const int dn = (d0 + 1 > D_ - 1) ? D_ - 1 : d0 + 1;
        const float* p2 = xb + dn * (H_ * W_);
        m0 = *(const float4v*)(p2 + rm);
        m1 = *(const float4v*)(p2 + rc);
        m2 = *(const float4v*)(p2 + rp);
    }

    const size_t dhw  = (size_t)D_ * H_ * W_;
    const size_t cdhw = (size_t)C_ * dhw;          // stride between kernel slots
    float* o = out + ((size_t)(b * 4) * C_ + c) * dhw
                   + ((size_t)d0 * H_ + h) * W_ + 4 * quad;

#pragma unroll
    for (int t = 0; t < DCHUNK; ++t) {
        const int d = d0 + t;

        // rows of plane d+1 (already in flight)
        float4v nqm = m0, nqc = m1, nqp = m2;

        // prefetch rows of plane d+2 (clamped; last iters reload plane 63, L1-hit)
        const int dn = (d + 2 > D_ - 1) ? D_ - 1 : d + 2;
        const float* pn = xb + dn * (H_ * W_);
        m0 = *(const float4v*)(pn + rm);
        m1 = *(const float4v*)(pn + rc);
        m2 = *(const float4v*)(pn + rp);

        // finish plane d+1 partials
        float4v A2, Bv2, Cc2;
        make_plane(nqm, nqc, nqp, quad, A2, Bv2, Cc2);

        // outputs at depth d
        float4v sx = (Bv0 + 2.0f * Bv1 + Bv2) * (1.0f / 16.0f);  // S_d S_h D_w
        float4v sy = (Cc0 + 2.0f * Cc1 + Cc2) * (1.0f / 16.0f);  // S_d D_h S_w
        float4v sz = (A2 - A0)               * (1.0f / 16.0f);   // D_d S_h S_w

        __builtin_nontemporal_store(q1, (float4v*)(o + 0 * cdhw));
        __builtin_nontemporal_store(sx, (float4v*)(o + 1 * cdhw));
        __builtin_nontemporal_store(sy, (float4v*)(o + 2 * cdhw));
        __builtin_nontemporal_store(sz, (float4v*)(o + 3 * cdhw));
        o += H_ * W_;

        // shift ring
        A0 = A1; Bv0 = Bv1; Cc0 = Cc1;
        A1 = A2; Bv1 = Bv2; Cc1 = Cc2;
        q1 = nqc;
    }
}

extern "C" void kernel_launch(void* const* d_in, const int* in_sizes, int n_in,
                              void* d_out, int out_size, void* d_ws, size_t ws_size,
                              hipStream_t stream) {
    (void)in_sizes; (void)n_in; (void)d_ws; (void)ws_size; (void)out_size;
    const float* x = (const float*)d_in[0];
    float* out = (float*)d_out;

    dim3 block(64, 4, 1);                       // wave = 16 w-quads x 4 h-rows
    dim3 grid(H_ / 16, D_ / DCHUNK, B_ * C_);   // 4 x 8 x 64 = 2048 blocks
    perceive3d_kernel<<<grid, block, 0, stream>>>(x, out);
}